// Round 1
// baseline (857.803 us; speedup 1.0000x reference)
//
#include <hip/hip_runtime.h>

// Problem constants: B=2, T=2048, E=1024, H=8, D=512, HD=4096.
// All internal compute in bf16 MFMA (threshold = 2% rel -> ample margin).

#define DEV __device__ __forceinline__

using bf16x8  = __attribute__((ext_vector_type(8))) short;
using floatx4 = __attribute__((ext_vector_type(4))) float;

#define MFMA16(a, b, c) __builtin_amdgcn_mfma_f32_16x16x32_bf16((a), (b), (c), 0, 0, 0)

DEV unsigned short f2bf(float f) {
  union { float f; unsigned int u; } c; c.f = f;
  unsigned int u = c.u + 0x7FFFu + ((c.u >> 16) & 1u);  // round-to-nearest-even
  return (unsigned short)(u >> 16);
}
DEV float bf2f(unsigned short h) {
  union { unsigned int u; float f; } c; c.u = ((unsigned int)h) << 16;
  return c.f;
}

// ---------------- cast fp32 -> bf16, 4 elements/thread ----------------
__global__ void cast_bf16_k(const float* __restrict__ src, unsigned short* __restrict__ dst, int n4) {
  int i = blockIdx.x * 256 + threadIdx.x;
  if (i >= n4) return;
  float4 v = ((const float4*)src)[i];
  uint2 o;
  o.x = (unsigned int)f2bf(v.x) | ((unsigned int)f2bf(v.y) << 16);
  o.y = (unsigned int)f2bf(v.z) | ((unsigned int)f2bf(v.w) << 16);
  ((uint2*)dst)[i] = o;
}

// ---------------- QKV projection GEMM ----------------
// C[m=b*2048+t][n=h*512+d] = sum_k X[m][k] * W[n][k]   (NT, both K-major)
// z selects W (0:Wq,1:Wk,2:Wv). Q,K stored [B,H,T,D]; V stored transposed [B,H,D,T].
__global__ __launch_bounds__(256) void qkv_gemm(
    const unsigned short* __restrict__ X,
    const unsigned short* __restrict__ Wq, const unsigned short* __restrict__ Wk,
    const unsigned short* __restrict__ Wv,
    unsigned short* __restrict__ Qo, unsigned short* __restrict__ Ko, unsigned short* __restrict__ Vo) {
  __shared__ __align__(16) unsigned short As[128 * 40];  // [128][32] padded to 40 (bank-safe)
  __shared__ __align__(16) unsigned short Bs[128 * 40];
  const int tid = threadIdx.x;
  const int wave = tid >> 6, lane = tid & 63, quad = lane >> 4, l16 = lane & 15;
  const int m0 = blockIdx.x * 128, n0 = blockIdx.y * 128;
  const int z = blockIdx.z;
  const unsigned short* W = (z == 0) ? Wq : (z == 1) ? Wk : Wv;
  const int wm = (wave >> 1) * 64, wn = (wave & 1) * 64;
  floatx4 acc[4][4];
#pragma unroll
  for (int i = 0; i < 4; ++i)
#pragma unroll
    for (int j = 0; j < 4; ++j) acc[i][j] = (floatx4){0.f, 0.f, 0.f, 0.f};

  for (int k0 = 0; k0 < 1024; k0 += 32) {
#pragma unroll
    for (int it = 0; it < 2; ++it) {
      int cid = it * 256 + tid;          // 512 chunks of 8 bf16
      int row = cid >> 2, cc = cid & 3;
      *(bf16x8*)(As + row * 40 + cc * 8) = *(const bf16x8*)(X + (size_t)(m0 + row) * 1024 + k0 + cc * 8);
      *(bf16x8*)(Bs + row * 40 + cc * 8) = *(const bf16x8*)(W + (size_t)(n0 + row) * 1024 + k0 + cc * 8);
    }
    __syncthreads();
    bf16x8 af[4], bw[4];
#pragma unroll
    for (int i = 0; i < 4; ++i) af[i] = *(const bf16x8*)(As + (wm + i * 16 + l16) * 40 + quad * 8);
#pragma unroll
    for (int j = 0; j < 4; ++j) bw[j] = *(const bf16x8*)(Bs + (wn + j * 16 + l16) * 40 + quad * 8);
#pragma unroll
    for (int i = 0; i < 4; ++i)
#pragma unroll
      for (int j = 0; j < 4; ++j) acc[i][j] = MFMA16(af[i], bw[j], acc[i][j]);
    __syncthreads();
  }
  // epilogue: C/D layout row=quad*4+r, col=l16
#pragma unroll
  for (int i = 0; i < 4; ++i)
#pragma unroll
    for (int j = 0; j < 4; ++j) {
      int gn = n0 + wn + j * 16 + l16;
      int h = gn >> 9, d = gn & 511;
#pragma unroll
      for (int r = 0; r < 4; ++r) {
        int gm = m0 + wm + i * 16 + quad * 4 + r;
        int b = gm >> 11, t = gm & 2047;
        unsigned short v = f2bf(acc[i][j][r]);
        if (z == 2)
          Vo[((size_t)((b * 8 + h) * 512 + d)) * 2048 + t] = v;   // V transposed [B,H,D,T]
        else
          ((z == 0) ? Qo : Ko)[((size_t)((b * 8 + h) * 2048 + t)) * 512 + d] = v;  // [B,H,T,D]
      }
    }
}

// ---------------- RoPE (in place, half-split pairs (i, i+256)) ----------------
__global__ void rope_k(unsigned short* __restrict__ Q, unsigned short* __restrict__ K) {
  int idx = blockIdx.x * 256 + threadIdx.x;      // 2 * 32768 rows * 256 pairs
  unsigned short* P = (idx & 8388608) ? K : Q;
  int r = idx & 8388607;
  int row = r >> 8;                              // (b*8+h)*2048 + t
  int i = r & 255;
  int t = row & 2047;
  size_t base = (size_t)row * 512;
  float x1 = bf2f(P[base + i]);
  float x2 = bf2f(P[base + i + 256]);
  float freq = expf(-(float)i * 0.03597789207803197f);  // ln(10000)/256
  float ang = (float)t * freq;
  float sv, cv;
  sincosf(ang, &sv, &cv);
  P[base + i]       = f2bf(x1 * cv - x2 * sv);
  P[base + i + 256] = f2bf(x1 * sv + x2 * cv);
}

// ---------------- flash attention (causal, online softmax) ----------------
// grid: (32 q-tiles swizzled, H, B); block 256 = 4 waves; wave w owns q-rows [qb+16w, qb+16w+15].
__global__ __launch_bounds__(256) void flash_attn(
    const unsigned short* __restrict__ Q, const unsigned short* __restrict__ K,
    const unsigned short* __restrict__ Vt, unsigned short* __restrict__ attn) {
  __shared__ __align__(16) unsigned short Ks[32 * 264];  // [32 s][256+8 d-half], padded
  __shared__ __align__(16) unsigned short Vs[512 * 40];  // [512 d][32+8 s], padded
  __shared__ __align__(16) unsigned short Ps[4 * 16 * 32];  // per-wave P tile
  const int tid = threadIdx.x;
  const int wave = tid >> 6, lane = tid & 63, quad = lane >> 4, l16 = lane & 15;
  int bx = blockIdx.x;
  const int qi = (bx & 1) ? (bx >> 1) : (31 - (bx >> 1));  // pair heavy/light diagonal blocks
  const int h = blockIdx.y, b = blockIdx.z;
  const size_t bh = ((size_t)(b * 8 + h)) << 20;  // * 2048*512
  const unsigned short* Qp = Q + bh;
  const unsigned short* Kp = K + bh;
  const unsigned short* Vp = Vt + bh;
  const int qb = qi * 64;

  // Q fragments: 16 k-steps of 32 dims (A-frag: m=l16, k=quad*8+j)
  bf16x8 qf[16];
  {
    const unsigned short* qrow = Qp + (size_t)(qb + wave * 16 + l16) * 512 + quad * 8;
#pragma unroll
    for (int ks = 0; ks < 16; ++ks) qf[ks] = *(const bf16x8*)(qrow + ks * 32);
  }
  floatx4 o[32];
#pragma unroll
  for (int n = 0; n < 32; ++n) o[n] = (floatx4){0.f, 0.f, 0.f, 0.f};
  float m_[4], l_[4];
#pragma unroll
  for (int r = 0; r < 4; ++r) { m_[r] = -3.0e38f; l_[r] = 0.f; }

  const int nst = 2 * qi + 2;  // causal: only tiles with s0 <= qb+63
  for (int st = 0; st < nst; ++st) {
    const int s0 = st * 32;
    // stage V^T tile [512][32] and K half0 [32][0:256)
#pragma unroll
    for (int it = 0; it < 8; ++it) {
      int cid = it * 256 + tid;
      int d = cid >> 2, c = cid & 3;
      *(bf16x8*)(Vs + d * 40 + c * 8) = *(const bf16x8*)(Vp + (size_t)d * 2048 + s0 + c * 8);
    }
#pragma unroll
    for (int it = 0; it < 4; ++it) {
      int cid = it * 256 + tid;
      int row = cid >> 5, cc = cid & 31;
      *(bf16x8*)(Ks + row * 264 + cc * 8) = *(const bf16x8*)(Kp + (size_t)(s0 + row) * 512 + cc * 8);
    }
    __syncthreads();
    floatx4 sc0 = (floatx4){0.f, 0.f, 0.f, 0.f}, sc1 = sc0;
#pragma unroll
    for (int ks = 0; ks < 8; ++ks) {
      bf16x8 k0v = *(const bf16x8*)(Ks + l16 * 264 + ks * 32 + quad * 8);
      bf16x8 k1v = *(const bf16x8*)(Ks + (16 + l16) * 264 + ks * 32 + quad * 8);
      sc0 = MFMA16(qf[ks], k0v, sc0);
      sc1 = MFMA16(qf[ks], k1v, sc1);
    }
    __syncthreads();  // all waves done with half0 before overwrite
#pragma unroll
    for (int it = 0; it < 4; ++it) {
      int cid = it * 256 + tid;
      int row = cid >> 5, cc = cid & 31;
      *(bf16x8*)(Ks + row * 264 + cc * 8) = *(const bf16x8*)(Kp + (size_t)(s0 + row) * 512 + 256 + cc * 8);
    }
    __syncthreads();
#pragma unroll
    for (int ks = 0; ks < 8; ++ks) {
      bf16x8 k0v = *(const bf16x8*)(Ks + l16 * 264 + ks * 32 + quad * 8);
      bf16x8 k1v = *(const bf16x8*)(Ks + (16 + l16) * 264 + ks * 32 + quad * 8);
      sc0 = MFMA16(qf[8 + ks], k0v, sc0);
      sc1 = MFMA16(qf[8 + ks], k1v, sc1);
    }
    // ---- online softmax (rows quad*4+r, cols l16 / l16+16) ----
    const float scale = 0.04419417382415922f;  // 1/sqrt(512)
    const int qrow0 = qb + wave * 16 + quad * 4;
    float pr0[4], pr1[4], mr[4];
#pragma unroll
    for (int r = 0; r < 4; ++r) {
      float a0 = sc0[r] * scale, a1 = sc1[r] * scale;
      if (s0 + l16 > qrow0 + r) a0 = -3.0e38f;        // causal mask
      if (s0 + 16 + l16 > qrow0 + r) a1 = -3.0e38f;
      pr0[r] = a0; pr1[r] = a1;
      mr[r] = fmaxf(a0, a1);
    }
#pragma unroll
    for (int off = 1; off < 16; off <<= 1)
#pragma unroll
      for (int r = 0; r < 4; ++r) mr[r] = fmaxf(mr[r], __shfl_xor(mr[r], off, 64));
    float alpha[4], rs[4];
#pragma unroll
    for (int r = 0; r < 4; ++r) {
      float mn = fmaxf(m_[r], mr[r]);
      alpha[r] = __expf(m_[r] - mn);
      m_[r] = mn;
      float p0 = __expf(pr0[r] - mn);
      float p1 = __expf(pr1[r] - mn);
      rs[r] = p0 + p1;
      Ps[wave * 512 + (quad * 4 + r) * 32 + l16] = f2bf(p0);
      Ps[wave * 512 + (quad * 4 + r) * 32 + 16 + l16] = f2bf(p1);
    }
#pragma unroll
    for (int off = 1; off < 16; off <<= 1)
#pragma unroll
      for (int r = 0; r < 4; ++r) rs[r] += __shfl_xor(rs[r], off, 64);
#pragma unroll
    for (int r = 0; r < 4; ++r) l_[r] = l_[r] * alpha[r] + rs[r];
#pragma unroll
    for (int n = 0; n < 32; ++n)
#pragma unroll
      for (int r = 0; r < 4; ++r) o[n][r] *= alpha[r];
    // ---- PV: O[16x512] += P[16x32] * V[32x512] ----
    bf16x8 pf = *(const bf16x8*)(Ps + wave * 512 + l16 * 32 + quad * 8);  // A-frag of P
#pragma unroll
    for (int nt = 0; nt < 32; ++nt) {
      bf16x8 vf = *(const bf16x8*)(Vs + (nt * 16 + l16) * 40 + quad * 8);  // B-frag from V^T
      o[nt] = MFMA16(pf, vf, o[nt]);
    }
    __syncthreads();  // done reading Vs/Ks before next tile stages
  }
  // ---- write attn [B,T,H*D] bf16 ----
  float inv[4];
#pragma unroll
  for (int r = 0; r < 4; ++r) inv[r] = 1.0f / l_[r];
  unsigned short* arow =
      attn + ((size_t)(b * 2048 + qb + wave * 16 + quad * 4)) * 4096 + h * 512 + l16;
#pragma unroll
  for (int nt = 0; nt < 32; ++nt)
#pragma unroll
    for (int r = 0; r < 4; ++r)
      arow[(size_t)r * 4096 + nt * 16] = f2bf(o[nt][r] * inv[r]);
}

// ---------------- output projection GEMM: out = attn @ Wo^T (fp32 out) ----------------
__global__ __launch_bounds__(256) void out_gemm(
    const unsigned short* __restrict__ A, const unsigned short* __restrict__ W,
    float* __restrict__ C) {
  __shared__ __align__(16) unsigned short As[128 * 40];
  __shared__ __align__(16) unsigned short Bs[128 * 40];
  const int tid = threadIdx.x;
  const int wave = tid >> 6, lane = tid & 63, quad = lane >> 4, l16 = lane & 15;
  const int m0 = blockIdx.x * 128, n0 = blockIdx.y * 128;
  const int wm = (wave >> 1) * 64, wn = (wave & 1) * 64;
  floatx4 acc[4][4];
#pragma unroll
  for (int i = 0; i < 4; ++i)
#pragma unroll
    for (int j = 0; j < 4; ++j) acc[i][j] = (floatx4){0.f, 0.f, 0.f, 0.f};
  for (int k0 = 0; k0 < 4096; k0 += 32) {
#pragma unroll
    for (int it = 0; it < 2; ++it) {
      int cid = it * 256 + tid;
      int row = cid >> 2, cc = cid & 3;
      *(bf16x8*)(As + row * 40 + cc * 8) = *(const bf16x8*)(A + (size_t)(m0 + row) * 4096 + k0 + cc * 8);
      *(bf16x8*)(Bs + row * 40 + cc * 8) = *(const bf16x8*)(W + (size_t)(n0 + row) * 4096 + k0 + cc * 8);
    }
    __syncthreads();
    bf16x8 af[4], bw[4];
#pragma unroll
    for (int i = 0; i < 4; ++i) af[i] = *(const bf16x8*)(As + (wm + i * 16 + l16) * 40 + quad * 8);
#pragma unroll
    for (int j = 0; j < 4; ++j) bw[j] = *(const bf16x8*)(Bs + (wn + j * 16 + l16) * 40 + quad * 8);
#pragma unroll
    for (int i = 0; i < 4; ++i)
#pragma unroll
      for (int j = 0; j < 4; ++j) acc[i][j] = MFMA16(af[i], bw[j], acc[i][j]);
    __syncthreads();
  }
#pragma unroll
  for (int i = 0; i < 4; ++i)
#pragma unroll
    for (int j = 0; j < 4; ++j) {
      int gn = n0 + wn + j * 16 + l16;
#pragma unroll
      for (int r = 0; r < 4; ++r) {
        int gm = m0 + wm + i * 16 + quad * 4 + r;
        C[(size_t)gm * 1024 + gn] = acc[i][j][r];
      }
    }
}

extern "C" void kernel_launch(void* const* d_in, const int* in_sizes, int n_in,
                              void* d_out, int out_size, void* d_ws, size_t ws_size,
                              hipStream_t stream) {
  const float* x  = (const float*)d_in[0];
  const float* Wq = (const float*)d_in[1];
  const float* Wk = (const float*)d_in[2];
  const float* Wv = (const float*)d_in[3];
  const float* Wo = (const float*)d_in[4];
  float* out = (float*)d_out;
  char* ws = (char*)d_ws;
  const size_t MB = 1048576;
  // Workspace layout (136 MB). attn reuses [0,32MB) after qkv_gemm is done with xb/wq/wk/wv.
  unsigned short* xb    = (unsigned short*)(ws + 0 * MB);
  unsigned short* wqb   = (unsigned short*)(ws + 8 * MB);
  unsigned short* wkb   = (unsigned short*)(ws + 16 * MB);
  unsigned short* wvb   = (unsigned short*)(ws + 24 * MB);
  unsigned short* attnb = (unsigned short*)(ws + 0 * MB);
  unsigned short* wob   = (unsigned short*)(ws + 32 * MB);
  unsigned short* Qb    = (unsigned short*)(ws + 40 * MB);
  unsigned short* Kb    = (unsigned short*)(ws + 72 * MB);
  unsigned short* Vb    = (unsigned short*)(ws + 104 * MB);  // transposed [B,H,D,T]

  const int n4 = 1048576;  // 4,194,304 / 4 for every tensor here
  cast_bf16_k<<<4096, 256, 0, stream>>>(x, xb, n4);
  cast_bf16_k<<<4096, 256, 0, stream>>>(Wq, wqb, n4);
  cast_bf16_k<<<4096, 256, 0, stream>>>(Wk, wkb, n4);
  cast_bf16_k<<<4096, 256, 0, stream>>>(Wv, wvb, n4);
  cast_bf16_k<<<4096, 256, 0, stream>>>(Wo, wob, n4);

  qkv_gemm<<<dim3(32, 32, 3), 256, 0, stream>>>(xb, wqb, wkb, wvb, Qb, Kb, Vb);
  rope_k<<<65536, 256, 0, stream>>>(Qb, Kb);
  flash_attn<<<dim3(32, 8, 2), 256, 0, stream>>>(Qb, Kb, Vb, attnb);
  out_gemm<<<dim3(32, 8), 256, 0, stream>>>(attnb, wob, out);
}

// Round 2
// 679.958 us; speedup vs baseline: 1.2616x; 1.2616x over previous
//
#include <hip/hip_runtime.h>

// B=2, T=2048, E=1024, H=8, D=512, HD=4096. bf16 MFMA internally.

#define DEV __device__ __forceinline__

using bf16x8  = __attribute__((ext_vector_type(8))) short;
using floatx4 = __attribute__((ext_vector_type(4))) float;

#define MFMA16(a, b, c) __builtin_amdgcn_mfma_f32_16x16x32_bf16((a), (b), (c), 0, 0, 0)

DEV unsigned short f2bf(float f) {
  union { float f; unsigned int u; } c; c.f = f;
  unsigned int u = c.u + 0x7FFFu + ((c.u >> 16) & 1u);
  return (unsigned short)(u >> 16);
}
DEV float bf2f(unsigned short h) {
  union { unsigned int u; float f; } c; c.u = ((unsigned int)h) << 16;
  return c.f;
}

// async global->LDS, 16B per lane. LDS dest = wave-uniform base + lane*16.
DEV void ldsld16(const unsigned short* g, unsigned short* l) {
  __builtin_amdgcn_global_load_lds(
      (__attribute__((address_space(1))) void*)(g),
      (__attribute__((address_space(3))) void*)(l), 16, 0, 0);
}

// ---------------- fused cast fp32 -> bf16 for all 5 tensors ----------------
__global__ void cast5_k(const float* __restrict__ x,  const float* __restrict__ wq,
                        const float* __restrict__ wk, const float* __restrict__ wv,
                        const float* __restrict__ wo,
                        unsigned short* __restrict__ xb,  unsigned short* __restrict__ wqb,
                        unsigned short* __restrict__ wkb, unsigned short* __restrict__ wvb,
                        unsigned short* __restrict__ wob) {
  const float* s; unsigned short* d;
  switch (blockIdx.y) {
    case 0: s = x;  d = xb;  break;
    case 1: s = wq; d = wqb; break;
    case 2: s = wk; d = wkb; break;
    case 3: s = wv; d = wvb; break;
    default: s = wo; d = wob; break;
  }
  int i = blockIdx.x * 256 + threadIdx.x;   // 4096 blocks * 256 = 1048576 float4s
  float4 v = ((const float4*)s)[i];
  uint2 o;
  o.x = (unsigned int)f2bf(v.x) | ((unsigned int)f2bf(v.y) << 16);
  o.y = (unsigned int)f2bf(v.z) | ((unsigned int)f2bf(v.w) << 16);
  ((uint2*)d)[i] = o;
}

// ---------------- QKV projection GEMM (global_load_lds staging) ----------------
__global__ __launch_bounds__(256) void qkv_gemm(
    const unsigned short* __restrict__ X,
    const unsigned short* __restrict__ Wq, const unsigned short* __restrict__ Wk,
    const unsigned short* __restrict__ Wv,
    unsigned short* __restrict__ Qo, unsigned short* __restrict__ Ko, unsigned short* __restrict__ Vo) {
  __shared__ __align__(16) unsigned short As[128 * 32];
  __shared__ __align__(16) unsigned short Bs[128 * 32];
  const int tid = threadIdx.x;
  const int wave = tid >> 6, lane = tid & 63, quad = lane >> 4, l16 = lane & 15;
  const int m0 = blockIdx.x * 128, n0 = blockIdx.y * 128;
  const int z = blockIdx.z;
  const unsigned short* W = (z == 0) ? Wq : (z == 1) ? Wk : Wv;
  const int wm = (wave >> 1) * 64, wn = (wave & 1) * 64;
  floatx4 acc[4][4];
#pragma unroll
  for (int i = 0; i < 4; ++i)
#pragma unroll
    for (int j = 0; j < 4; ++j) acc[i][j] = (floatx4){0.f, 0.f, 0.f, 0.f};

  const int r0 = wave * 32;
  const int lrow = lane >> 2, lchunk = (lane & 3) * 8;
  for (int k0 = 0; k0 < 1024; k0 += 32) {
    const unsigned short* ga = X + (size_t)(m0 + r0 + lrow) * 1024 + k0 + lchunk;
    const unsigned short* gb = W + (size_t)(n0 + r0 + lrow) * 1024 + k0 + lchunk;
    ldsld16(ga, As + r0 * 32);
    ldsld16(ga + (size_t)16 * 1024, As + r0 * 32 + 512);
    ldsld16(gb, Bs + r0 * 32);
    ldsld16(gb + (size_t)16 * 1024, Bs + r0 * 32 + 512);
    __syncthreads();
    bf16x8 af[4], bw[4];
#pragma unroll
    for (int i = 0; i < 4; ++i) af[i] = *(const bf16x8*)(As + (wm + i * 16 + l16) * 32 + quad * 8);
#pragma unroll
    for (int j = 0; j < 4; ++j) bw[j] = *(const bf16x8*)(Bs + (wn + j * 16 + l16) * 32 + quad * 8);
#pragma unroll
    for (int i = 0; i < 4; ++i)
#pragma unroll
      for (int j = 0; j < 4; ++j) acc[i][j] = MFMA16(af[i], bw[j], acc[i][j]);
    __syncthreads();
  }
#pragma unroll
  for (int i = 0; i < 4; ++i)
#pragma unroll
    for (int j = 0; j < 4; ++j) {
      int gn = n0 + wn + j * 16 + l16;
      int h = gn >> 9, d = gn & 511;
#pragma unroll
      for (int r = 0; r < 4; ++r) {
        int gm = m0 + wm + i * 16 + quad * 4 + r;
        int b = gm >> 11, t = gm & 2047;
        unsigned short v = f2bf(acc[i][j][r]);
        if (z == 2)
          Vo[((size_t)((b * 8 + h) * 512 + d)) * 2048 + t] = v;   // V^T [B,H,D,T]
        else
          ((z == 0) ? Qo : Ko)[((size_t)((b * 8 + h) * 2048 + t)) * 512 + d] = v;
      }
    }
}

// ---------------- RoPE ----------------
__global__ void rope_k(unsigned short* __restrict__ Q, unsigned short* __restrict__ K) {
  int idx = blockIdx.x * 256 + threadIdx.x;
  unsigned short* P = (idx & 8388608) ? K : Q;
  int r = idx & 8388607;
  int row = r >> 8;
  int i = r & 255;
  int t = row & 2047;
  size_t base = (size_t)row * 512;
  float x1 = bf2f(P[base + i]);
  float x2 = bf2f(P[base + i + 256]);
  float freq = expf(-(float)i * 0.03597789207803197f);
  float ang = (float)t * freq;
  float sv, cv;
  sincosf(ang, &sv, &cv);
  P[base + i]       = f2bf(x1 * cv - x2 * sv);
  P[base + i + 256] = f2bf(x1 * sv + x2 * cv);
}

// ---------------- flash attention (causal, online softmax, s-split) ----------------
// grid (16 bh, NW). bh fastest so heavy chunks hit all CUs first.
// split: y<16 -> qi=31-y chunk0 (s-tiles 0..31, out=partial P1); y in [16,32) ->
// qi=47-y chunk1 (s-tiles 32..nst, out=attn unnormalized + ml2); y>=32 -> qi=47-y
// single chunk direct. non-split: y<16 -> qi=31-y else qi=y-16 (CU pairing balance).
__global__ __launch_bounds__(256) void flash_attn(
    const unsigned short* __restrict__ Q, const unsigned short* __restrict__ K,
    const unsigned short* __restrict__ Vt, unsigned short* __restrict__ attn,
    unsigned short* __restrict__ P1, float* __restrict__ ml1, float* __restrict__ ml2,
    int split) {
  __shared__ __align__(16) unsigned short Ks[32 * 264];
  __shared__ __align__(16) unsigned short Vs[512 * 40];
  __shared__ __align__(16) unsigned short Ps[4 * 16 * 32];
  const int tid = threadIdx.x;
  const int wave = tid >> 6, lane = tid & 63, quad = lane >> 4, l16 = lane & 15;
  const int bh = blockIdx.x, b = bh >> 3, h = bh & 7;
  const int y = blockIdx.y;
  int qi, st0, stN, om;  // om: 0 direct, 1 partial1, 2 chunk1->attn unnormalized
  if (split) {
    if (y < 16)      { qi = 31 - y;  st0 = 0;  stN = 32;         om = 1; }
    else if (y < 32) { qi = 47 - y;  st0 = 32; stN = 2 * qi + 2; om = 2; }
    else             { qi = 47 - y;  st0 = 0;  stN = 2 * qi + 2; om = 0; }
  } else {
    qi = (y < 16) ? (31 - y) : (y - 16);
    st0 = 0; stN = 2 * qi + 2; om = 0;
  }
  const size_t bhoff = ((size_t)bh) << 20;
  const unsigned short* Qp = Q + bhoff;
  const unsigned short* Kp = K + bhoff;
  const unsigned short* Vp = Vt + bhoff;
  const int qb = qi * 64;

  bf16x8 qf[16];
  {
    const unsigned short* qrow = Qp + (size_t)(qb + wave * 16 + l16) * 512 + quad * 8;
#pragma unroll
    for (int ks = 0; ks < 16; ++ks) qf[ks] = *(const bf16x8*)(qrow + ks * 32);
  }
  floatx4 o[32];
#pragma unroll
  for (int n = 0; n < 32; ++n) o[n] = (floatx4){0.f, 0.f, 0.f, 0.f};
  float m_[4], l_[4];
#pragma unroll
  for (int r = 0; r < 4; ++r) { m_[r] = -3.0e38f; l_[r] = 0.f; }

  for (int st = st0; st < stN; ++st) {
    const int s0 = st * 32;
#pragma unroll
    for (int it = 0; it < 8; ++it) {
      int cid = it * 256 + tid;
      int d = cid >> 2, c = cid & 3;
      *(bf16x8*)(Vs + d * 40 + c * 8) = *(const bf16x8*)(Vp + (size_t)d * 2048 + s0 + c * 8);
    }
#pragma unroll
    for (int it = 0; it < 4; ++it) {
      int cid = it * 256 + tid;
      int row = cid >> 5, cc = cid & 31;
      *(bf16x8*)(Ks + row * 264 + cc * 8) = *(const bf16x8*)(Kp + (size_t)(s0 + row) * 512 + cc * 8);
    }
    __syncthreads();
    floatx4 sc0 = (floatx4){0.f, 0.f, 0.f, 0.f}, sc1 = sc0;
#pragma unroll
    for (int ks = 0; ks < 8; ++ks) {
      bf16x8 k0v = *(const bf16x8*)(Ks + l16 * 264 + ks * 32 + quad * 8);
      bf16x8 k1v = *(const bf16x8*)(Ks + (16 + l16) * 264 + ks * 32 + quad * 8);
      sc0 = MFMA16(qf[ks], k0v, sc0);
      sc1 = MFMA16(qf[ks], k1v, sc1);
    }
    __syncthreads();
#pragma unroll
    for (int it = 0; it < 4; ++it) {
      int cid = it * 256 + tid;
      int row = cid >> 5, cc = cid & 31;
      *(bf16x8*)(Ks + row * 264 + cc * 8) = *(const bf16x8*)(Kp + (size_t)(s0 + row) * 512 + 256 + cc * 8);
    }
    __syncthreads();
#pragma unroll
    for (int ks = 0; ks < 8; ++ks) {
      bf16x8 k0v = *(const bf16x8*)(Ks + l16 * 264 + ks * 32 + quad * 8);
      bf16x8 k1v = *(const bf16x8*)(Ks + (16 + l16) * 264 + ks * 32 + quad * 8);
      sc0 = MFMA16(qf[8 + ks], k0v, sc0);
      sc1 = MFMA16(qf[8 + ks], k1v, sc1);
    }
    const float scale = 0.04419417382415922f;  // 1/sqrt(512)
    const int qrow0 = qb + wave * 16 + quad * 4;
    float pr0[4], pr1[4], mr[4];
#pragma unroll
    for (int r = 0; r < 4; ++r) {
      float a0 = sc0[r] * scale, a1 = sc1[r] * scale;
      if (s0 + l16 > qrow0 + r) a0 = -3.0e38f;
      if (s0 + 16 + l16 > qrow0 + r) a1 = -3.0e38f;
      pr0[r] = a0; pr1[r] = a1;
      mr[r] = fmaxf(a0, a1);
    }
#pragma unroll
    for (int off = 1; off < 16; off <<= 1)
#pragma unroll
      for (int r = 0; r < 4; ++r) mr[r] = fmaxf(mr[r], __shfl_xor(mr[r], off, 64));
    float alpha[4], rs[4];
#pragma unroll
    for (int r = 0; r < 4; ++r) {
      float mn = fmaxf(m_[r], mr[r]);
      alpha[r] = __expf(m_[r] - mn);
      m_[r] = mn;
      float p0 = __expf(pr0[r] - mn);
      float p1 = __expf(pr1[r] - mn);
      rs[r] = p0 + p1;
      Ps[wave * 512 + (quad * 4 + r) * 32 + l16] = f2bf(p0);
      Ps[wave * 512 + (quad * 4 + r) * 32 + 16 + l16] = f2bf(p1);
    }
#pragma unroll
    for (int off = 1; off < 16; off <<= 1)
#pragma unroll
      for (int r = 0; r < 4; ++r) rs[r] += __shfl_xor(rs[r], off, 64);
#pragma unroll
    for (int r = 0; r < 4; ++r) l_[r] = l_[r] * alpha[r] + rs[r];
    // skip O-rescale when no row's max moved (alpha==1 exactly)
    if (__any(alpha[0] + alpha[1] + alpha[2] + alpha[3] < 4.0f)) {
#pragma unroll
      for (int n = 0; n < 32; ++n)
#pragma unroll
        for (int r = 0; r < 4; ++r) o[n][r] *= alpha[r];
    }
    bf16x8 pf = *(const bf16x8*)(Ps + wave * 512 + l16 * 32 + quad * 8);
#pragma unroll
    for (int nt = 0; nt < 32; ++nt) {
      bf16x8 vf = *(const bf16x8*)(Vs + (nt * 16 + l16) * 40 + quad * 8);
      o[nt] = MFMA16(pf, vf, o[nt]);
    }
    __syncthreads();
  }
  // ---- outputs ----
  const int rowi = wave * 16 + quad * 4;  // +r
  if (om == 0) {
    float inv[4];
#pragma unroll
    for (int r = 0; r < 4; ++r) inv[r] = 1.0f / l_[r];
    unsigned short* arow = attn + ((size_t)(b * 2048 + qb + rowi)) * 4096 + h * 512 + l16;
#pragma unroll
    for (int nt = 0; nt < 32; ++nt)
#pragma unroll
      for (int r = 0; r < 4; ++r)
        arow[(size_t)r * 4096 + nt * 16] = f2bf(o[nt][r] * inv[r]);
  } else {
    const int p = bh * 16 + (qi - 16);
    float* ml = (om == 1) ? ml1 : ml2;
    if (l16 == 0) {
#pragma unroll
      for (int r = 0; r < 4; ++r) {
        ml[(size_t)p * 128 + (rowi + r) * 2]     = m_[r];
        ml[(size_t)p * 128 + (rowi + r) * 2 + 1] = l_[r];
      }
    }
    if (om == 1) {
      unsigned short* prow = P1 + ((size_t)p * 64 + rowi) * 512 + l16;
#pragma unroll
      for (int nt = 0; nt < 32; ++nt)
#pragma unroll
        for (int r = 0; r < 4; ++r)
          prow[(size_t)r * 512 + nt * 16] = f2bf(o[nt][r]);   // unnormalized
    } else {
      unsigned short* arow = attn + ((size_t)(b * 2048 + qb + rowi)) * 4096 + h * 512 + l16;
#pragma unroll
      for (int nt = 0; nt < 32; ++nt)
#pragma unroll
        for (int r = 0; r < 4; ++r)
          arow[(size_t)r * 4096 + nt * 16] = f2bf(o[nt][r]);  // unnormalized
    }
  }
}

// ---------------- combine partials (split mode only, qi>=16) ----------------
__global__ void combine_k(const unsigned short* __restrict__ P1,
                          const float* __restrict__ ml1, const float* __restrict__ ml2,
                          unsigned short* __restrict__ attn) {
  const int p = blockIdx.x;  // [0,256)
  const int bh = p >> 4, b = bh >> 3, h = bh & 7, qi = 16 + (p & 15);
  const int tid = threadIdx.x;
#pragma unroll
  for (int it = 0; it < 16; ++it) {
    int idx = it * 256 + tid;
    int r = idx >> 6, dc = idx & 63;
    float m1 = ml1[(size_t)p * 128 + r * 2], l1 = ml1[(size_t)p * 128 + r * 2 + 1];
    float m2 = ml2[(size_t)p * 128 + r * 2], l2 = ml2[(size_t)p * 128 + r * 2 + 1];
    float M = fmaxf(m1, m2);
    float w1 = __expf(m1 - M), w2 = __expf(m2 - M);
    float inv = 1.0f / (l1 * w1 + l2 * w2);
    const unsigned short* o1 = P1 + ((size_t)p * 64 + r) * 512 + dc * 8;
    unsigned short* ap = attn + ((size_t)(b * 2048 + qi * 64 + r)) * 4096 + h * 512 + dc * 8;
    unsigned short res[8];
#pragma unroll
    for (int j = 0; j < 8; ++j)
      res[j] = f2bf((bf2f(o1[j]) * w1 + bf2f(ap[j]) * w2) * inv);
    *(bf16x8*)ap = *(bf16x8*)res;
  }
}

// ---------------- output projection: out += attn @ Wo^T (split-K, fp32 atomics) ----------------
__global__ __launch_bounds__(256) void out_gemm(
    const unsigned short* __restrict__ A, const unsigned short* __restrict__ W,
    float* __restrict__ C) {
  __shared__ __align__(16) unsigned short As[128 * 32];
  __shared__ __align__(16) unsigned short Bs[128 * 32];
  const int tid = threadIdx.x;
  const int wave = tid >> 6, lane = tid & 63, quad = lane >> 4, l16 = lane & 15;
  const int m0 = blockIdx.x * 128, n0 = blockIdx.y * 128;
  const int kb = blockIdx.z * 1024;
  const int wm = (wave >> 1) * 64, wn = (wave & 1) * 64;
  floatx4 acc[4][4];
#pragma unroll
  for (int i = 0; i < 4; ++i)
#pragma unroll
    for (int j = 0; j < 4; ++j) acc[i][j] = (floatx4){0.f, 0.f, 0.f, 0.f};
  const int r0 = wave * 32;
  const int lrow = lane >> 2, lchunk = (lane & 3) * 8;
  for (int k0 = kb; k0 < kb + 1024; k0 += 32) {
    const unsigned short* ga = A + (size_t)(m0 + r0 + lrow) * 4096 + k0 + lchunk;
    const unsigned short* gb = W + (size_t)(n0 + r0 + lrow) * 4096 + k0 + lchunk;
    ldsld16(ga, As + r0 * 32);
    ldsld16(ga + (size_t)16 * 4096, As + r0 * 32 + 512);
    ldsld16(gb, Bs + r0 * 32);
    ldsld16(gb + (size_t)16 * 4096, Bs + r0 * 32 + 512);
    __syncthreads();
    bf16x8 af[4], bw[4];
#pragma unroll
    for (int i = 0; i < 4; ++i) af[i] = *(const bf16x8*)(As + (wm + i * 16 + l16) * 32 + quad * 8);
#pragma unroll
    for (int j = 0; j < 4; ++j) bw[j] = *(const bf16x8*)(Bs + (wn + j * 16 + l16) * 32 + quad * 8);
#pragma unroll
    for (int i = 0; i < 4; ++i)
#pragma unroll
      for (int j = 0; j < 4; ++j) acc[i][j] = MFMA16(af[i], bw[j], acc[i][j]);
    __syncthreads();
  }
#pragma unroll
  for (int i = 0; i < 4; ++i)
#pragma unroll
    for (int j = 0; j < 4; ++j) {
      int gn = n0 + wn + j * 16 + l16;
#pragma unroll
      for (int r = 0; r < 4; ++r) {
        int gm = m0 + wm + i * 16 + quad * 4 + r;
        unsafeAtomicAdd(&C[(size_t)gm * 1024 + gn], acc[i][j][r]);
      }
    }
}

extern "C" void kernel_launch(void* const* d_in, const int* in_sizes, int n_in,
                              void* d_out, int out_size, void* d_ws, size_t ws_size,
                              hipStream_t stream) {
  const float* x  = (const float*)d_in[0];
  const float* Wq = (const float*)d_in[1];
  const float* Wk = (const float*)d_in[2];
  const float* Wv = (const float*)d_in[3];
  const float* Wo = (const float*)d_in[4];
  float* out = (float*)d_out;
  char* ws = (char*)d_ws;
  const size_t MB = 1048576;
  unsigned short* xb    = (unsigned short*)(ws + 0 * MB);
  unsigned short* wqb   = (unsigned short*)(ws + 8 * MB);
  unsigned short* wkb   = (unsigned short*)(ws + 16 * MB);
  unsigned short* wvb   = (unsigned short*)(ws + 24 * MB);
  unsigned short* wob   = (unsigned short*)(ws + 32 * MB);
  unsigned short* Qb    = (unsigned short*)(ws + 40 * MB);
  unsigned short* Kb    = (unsigned short*)(ws + 72 * MB);
  unsigned short* Vb    = (unsigned short*)(ws + 104 * MB);
  unsigned short* attnb = (unsigned short*)(ws + 0 * MB);   // reuse (dead post-qkv)
  unsigned short* P1    = (unsigned short*)(ws + 136 * MB); // 16 MB (split mode)
  float* ml1            = (float*)(ws + 152 * MB);          // 128 KB
  float* ml2            = (float*)(ws + 152 * MB + 131072); // 128 KB
  const int split = (ws_size >= (size_t)160 * MB) ? 1 : 0;

  hipMemsetAsync(d_out, 0, (size_t)4096 * 1024 * 4, stream);  // out_gemm accumulates

  cast5_k<<<dim3(4096, 5), 256, 0, stream>>>(x, Wq, Wk, Wv, Wo, xb, wqb, wkb, wvb, wob);
  qkv_gemm<<<dim3(32, 32, 3), 256, 0, stream>>>(xb, wqb, wkb, wvb, Qb, Kb, Vb);
  rope_k<<<65536, 256, 0, stream>>>(Qb, Kb);
  flash_attn<<<dim3(16, split ? 48 : 32), 256, 0, stream>>>(Qb, Kb, Vb, attnb, P1, ml1, ml2, split);
  if (split) combine_k<<<256, 256, 0, stream>>>(P1, ml1, ml2, attnb);
  out_gemm<<<dim3(32, 8, 4), 256, 0, stream>>>(attnb, wob, out);
}